// Round 8
// baseline (167.057 us; speedup 1.0000x reference)
//
#include <hip/hip_runtime.h>

#define HH 128
#define WW 128
#define NPIX 16384
#define NC 32
#define NO 32
#define KS 9
#define TAPS 81
#define DIL 2
#define PAD 8
#define SMAX 27.6310211159f   // s<=SMAX <=> exp(-0.5s)>=1e-6; dropped-tap err measured ~1e-4
#define NW (NO * NC * TAPS)   // 82944

// ---------------------------------------------------------------------------
// prep: grid (2, 128+41), block 512.
//  y<128 : block (wseg,h) stages f for 9 dilated rows x 32 ch x 80-col window
//          (93 KB LDS, 1 block/CU). Wave wy handles taps {wy, wy+8, ...}:
//          full-channel s from LDS -> kv (dense, 0 at invalid) -> kbuf;
//          per-(wave-of-px,row) live mask assembled via LDS atomicOr.
//  y>=128: 82 blocks transpose W1,W2 -> [tap][cq][oq][ot*64+o*8+cc]
//          (wave-uniform s_load layout for pac).
// ---------------------------------------------------------------------------
__global__ __launch_bounds__(512, 1) void prep_kernel(
    const float* __restrict__ f,
    const float* __restrict__ W1, const float* __restrict__ W2,
    float* __restrict__ kbuf, unsigned* __restrict__ live9,
    float* __restrict__ W1t, float* __restrict__ W2t)
{
    if (blockIdx.y >= HH) {
        int tb = (blockIdx.y - HH) * 2 + blockIdx.x;     // 0..81
        for (int t = tb * 512 + threadIdx.x; t < NW; t += 82 * 512) {
            int o = t / (NC * TAPS);
            int r = t - o * (NC * TAPS);
            int c = r / TAPS;
            int tap = r - c * TAPS;
            int d = ((tap * 4 + (c >> 3)) * 2 + (o >> 4)) * 128
                    + ((o >> 3) & 1) * 64 + (o & 7) * 8 + (c & 7);
            W1t[d] = W1[t];
            W2t[d] = W2[t];
        }
        return;
    }
    __shared__ float sf[KS][NC][81];      // 93312 B; 80-col window +1 pad
    __shared__ unsigned lmask[KS];
    const int h = blockIdx.y, wseg = blockIdx.x;
    const int col0 = wseg * 64 - PAD;
    if (threadIdx.x < KS) lmask[threadIdx.x] = 0u;
    for (int idx = threadIdx.x; idx < KS * NC * 80; idx += 512) {
        int col = idx % 80;
        int rc = idx / 80;
        int c = rc & (NC - 1);
        int r = rc >> 5;
        int qh = h + DIL * r - PAD;
        qh = qh < 0 ? 0 : (qh > HH - 1 ? HH - 1 : qh);
        int qw = col0 + col;
        qw = qw < 0 ? 0 : (qw > WW - 1 ? WW - 1 : qw);
        sf[r][c][col] = f[c * NPIX + qh * WW + qw];
    }
    __syncthreads();
    const int wy = threadIdx.x >> 6;      // wave -> tap subset
    const int l = threadIdx.x & 63;
    const int px = wseg * 64 + l;
    const int pix = h * WW + px;
    float fc[NC];
#pragma unroll
    for (int c = 0; c < NC; ++c) fc[c] = sf[4][c][l + PAD];
    for (int tap = wy; tap < TAPS; tap += 8) {   // wave-uniform trip count
        int i = tap / KS, j = tap - i * KS;
        int qh = h + DIL * i - PAD;
        int qw = px + DIL * j - PAD;
        bool valid = ((unsigned)qh < HH) & ((unsigned)qw < WW);
        int ci = l + DIL * j;                    // 0..79, always in window
        float s0 = 0.f, s1 = 0.f, s2 = 0.f, s3 = 0.f;
#pragma unroll
        for (int c = 0; c < NC; c += 4) {
            float d0 = sf[i][c + 0][ci] - fc[c + 0];
            float d1 = sf[i][c + 1][ci] - fc[c + 1];
            float d2 = sf[i][c + 2][ci] - fc[c + 2];
            float d3 = sf[i][c + 3][ci] - fc[c + 3];
            s0 = fmaf(d0, d0, s0); s1 = fmaf(d1, d1, s1);
            s2 = fmaf(d2, d2, s2); s3 = fmaf(d3, d3, s3);
        }
        float s = (s0 + s1) + (s2 + s3);
        kbuf[tap * NPIX + pix] = valid ? __expf(-0.5f * s) : 0.f;
        bool live = valid && (s <= SMAX);
        if (__ballot(live) && l == 0) atomicOr(&lmask[i], 1u << j);
    }
    __syncthreads();
    if (threadIdx.x < KS)
        live9[(2 * h + wseg) * KS + threadIdx.x] = lmask[threadIdx.x];
}

// ---------------------------------------------------------------------------
// pac: grid (128 h, 4 cq, 2 oq), block 256 = 128 px x 2 ot. LDS = x-stage
// only (37 KB -> 4 blocks/CU = 16 waves/CU = 4/SIMD). Per thread: o=8, c=8.
// kv prefetched for 8 live taps per batch (one exposed latency per 8 taps);
// weights via wave-uniform s_load (scalar pipe); x from LDS (conflict-free).
// Partials to part[cq] -- no atomics.
// ---------------------------------------------------------------------------
__global__ __launch_bounds__(256, 4) void pac_kernel(
    const float* __restrict__ in, const float* __restrict__ kbuf,
    const unsigned* __restrict__ live9, const float* __restrict__ Wt,
    float* __restrict__ part)
{
    __shared__ float sx[KS][8][WW + 1];   // 37152 B
    const int h = blockIdx.x, cq = blockIdx.y, oq = blockIdx.z;
    const int cb = cq * 8;
    for (int idx = threadIdx.x; idx < KS * 8 * WW; idx += 256) {
        int px = idx & (WW - 1);
        int t = idx >> 7;
        int cc = t & 7, r = t >> 3;
        int qh = h + DIL * r - PAD;
        qh = qh < 0 ? 0 : (qh > HH - 1 ? HH - 1 : qh);
        sx[r][cc][px] = in[(cb + cc) * NPIX + qh * WW + px];
    }
    __syncthreads();
    const int px = threadIdx.x & 127;
    const int ot = threadIdx.x >> 7;      // wave-uniform (waves 0,1 / 2,3)
    const int pix = h * WW + px;
    const int wv = 2 * h + (px >> 6);     // wave-uniform

    int i = 0;
    unsigned m = (unsigned)__builtin_amdgcn_readfirstlane((int)live9[wv * KS + 0]);
    auto next = [&]() -> int {            // wave-uniform live-tap iterator
        while (m == 0) {
            if (++i >= KS) return -1;
            m = (unsigned)__builtin_amdgcn_readfirstlane((int)live9[wv * KS + i]);
        }
        int j = __builtin_ctz(m);
        m &= m - 1;
        return i * KS + j;
    };

    float acc[8];
#pragma unroll
    for (int o = 0; o < 8; ++o) acc[o] = 0.f;

    for (;;) {
        int tp[8];
#pragma unroll
        for (int u = 0; u < 8; ++u) tp[u] = next();   // -1 padded when exhausted
        if (tp[0] < 0) break;
        float kv[8];
#pragma unroll
        for (int u = 0; u < 8; ++u) {                 // independent batch
            int tt = tp[u] < 0 ? tp[0] : tp[u];
            kv[u] = kbuf[tt * NPIX + pix];
        }
#pragma unroll
        for (int u = 0; u < 8; ++u) {
            if (tp[u] < 0) break;                     // wave-uniform
            int tap = tp[u];
            int ii = tap / KS, j = tap - ii * KS;
            int qw = px + DIL * j - PAD;
            qw = qw < 0 ? 0 : (qw > WW - 1 ? WW - 1 : qw);  // kv==0 masks OOB
            float x[8];
#pragma unroll
            for (int cc = 0; cc < 8; ++cc) x[cc] = sx[ii][cc][qw];
            const float* wp = Wt + ((tap * 4 + cq) * 2 + oq) * 128 + ot * 64;
#pragma unroll
            for (int o = 0; o < 8; ++o) {
                float t = 0.f;
#pragma unroll
                for (int cc = 0; cc < 8; ++cc)
                    t = fmaf(x[cc], wp[o * 8 + cc], t);
                acc[o] = fmaf(kv[u], t, acc[o]);
            }
        }
        if (tp[7] < 0) break;
    }

#pragma unroll
    for (int o = 0; o < 8; ++o)
        part[(cq * NO + oq * 16 + ot * 8 + o) * NPIX + pix] = acc[o];
}

// ---------------------------------------------------------------------------
// reduce: out[o,p] = bias[o] + sum_cq part[cq][o][p]. Fully coalesced.
// ---------------------------------------------------------------------------
__global__ __launch_bounds__(256) void reduce_kernel(
    const float* __restrict__ part, const float* __restrict__ bias,
    float* __restrict__ out)
{
    int tid = blockIdx.x * 256 + threadIdx.x;    // NO*NPIX
    int o = tid >> 14;
    out[tid] = bias[o] + (part[tid] + part[NO * NPIX + tid])
             + (part[2 * NO * NPIX + tid] + part[3 * NO * NPIX + tid]);
}

// ---------------------------------------------------------------------------
// Fallback (round-1 proven path, 2 MB ws) in case ws is small.
// ---------------------------------------------------------------------------
#define CHUNK 27
#define NCHUNK 3
#define KMIN 1e-6f
__global__ __launch_bounds__(256) void pac_layer_fuse(
    const float* __restrict__ in, const float* __restrict__ f,
    const float* __restrict__ Wt, const float* __restrict__ bias,
    float* __restrict__ out)
{
    __shared__ float wl[NC * CHUNK * 8];
    const int og = blockIdx.y;
    const int pix = blockIdx.x * 256 + threadIdx.x;
    const int h = pix >> 7, w = pix & (WW - 1);
    float acc[8];
#pragma unroll
    for (int i = 0; i < 8; ++i) acc[i] = 0.f;
    float fc[NC];
#pragma unroll
    for (int c = 0; c < NC; ++c) fc[c] = f[c * NPIX + pix];
    for (int ch = 0; ch < NCHUNK; ++ch) {
        __syncthreads();
        for (int idx = threadIdx.x; idx < NC * CHUNK * 8; idx += 256) {
            int t = idx % CHUNK;
            int c = (idx / CHUNK) % NC;
            int o = idx / (CHUNK * NC);
            wl[(c * CHUNK + t) * 8 + o] =
                Wt[(og * 8 + o) * (NC * TAPS) + c * TAPS + ch * CHUNK + t];
        }
        __syncthreads();
        for (int t = 0; t < CHUNK; ++t) {
            int tap = ch * CHUNK + t;
            int qh = h + (tap / KS) * DIL - PAD;
            int qw = w + (tap % KS) * DIL - PAD;
            bool valid = ((unsigned)qh < HH) & ((unsigned)qw < WW);
            int q = qh * WW + qw;
            float s = 0.f;
#pragma unroll
            for (int c = 0; c < NC; ++c) {
                float fn = valid ? f[c * NPIX + q] : 0.f;
                float d = fn - fc[c];
                s = fmaf(d, d, s);
            }
            float kv = __expf(-0.5f * s);
            if (__all((kv < KMIN) | (!valid))) continue;
            const float* wpp = &wl[t * 8];
#pragma unroll 8
            for (int c = 0; c < NC; ++c) {
                float v = valid ? in[c * NPIX + q] : 0.f;
                v *= kv;
#pragma unroll
                for (int o = 0; o < 8; ++o)
                    acc[o] = fmaf(v, wpp[c * CHUNK * 8 + o], acc[o]);
            }
        }
    }
#pragma unroll
    for (int o = 0; o < 8; ++o)
        out[(og * 8 + o) * NPIX + pix] = acc[o] + bias[og * 8 + o];
}

// ---------------------------------------------------------------------------
extern "C" void kernel_launch(void* const* d_in, const int* in_sizes, int n_in,
                              void* d_out, int out_size, void* d_ws, size_t ws_size,
                              hipStream_t stream)
{
    (void)in_sizes; (void)n_in; (void)out_size;
    const float* x  = (const float*)d_in[0];
    const float* f  = (const float*)d_in[1];
    const float* W1 = (const float*)d_in[2];
    const float* b1 = (const float*)d_in[3];
    const float* W2 = (const float*)d_in[4];
    const float* b2 = (const float*)d_in[5];
    float* out = (float*)d_out;

    float* ws = (float*)d_ws;
    float* kbuf = ws;                                    // TAPS*NPIX
    unsigned* live9 = (unsigned*)(kbuf + TAPS * NPIX);   // 2304 (pad 2560)
    float* W1t = kbuf + TAPS * NPIX + 2560;              // NW
    float* W2t = W1t + NW;                               // NW
    float* part = W2t + NW;                              // 4*NO*NPIX
    float* ht = part + 4 * NO * NPIX;                    // NO*NPIX
    const size_t need =
        (size_t)(TAPS * NPIX + 2560 + 2 * NW + 5 * NO * NPIX) * sizeof(float);

    if (ws_size >= need) {
        prep_kernel<<<dim3(2, HH + 41), 512, 0, stream>>>(
            f, W1, W2, kbuf, live9, W1t, W2t);
        pac_kernel<<<dim3(HH, 4, 2), 256, 0, stream>>>(x, kbuf, live9, W1t, part);
        reduce_kernel<<<NO * NPIX / 256, 256, 0, stream>>>(part, b1, ht);
        pac_kernel<<<dim3(HH, 4, 2), 256, 0, stream>>>(ht, kbuf, live9, W2t, part);
        reduce_kernel<<<NO * NPIX / 256, 256, 0, stream>>>(part, b2, out);
    } else {
        float* hbuf = ws;
        pac_layer_fuse<<<dim3(64, 4), 256, 0, stream>>>(x, f, W1, b1, hbuf);
        pac_layer_fuse<<<dim3(64, 4), 256, 0, stream>>>(hbuf, f, W2, b2, out);
    }
}